// Round 5
// baseline (1044.515 us; speedup 1.0000x reference)
//
#include <hip/hip_runtime.h>
#include <hip/hip_bf16.h>
#include <stdint.h>

#define B_ 256
#define S_ 256
#define D_ 1024
#define P_ 512
#define SH 254            /* S-2 */
#define M_ (B_*SH)        /* 65024 */
#define EPSF 1e-7f

typedef __attribute__((ext_vector_type(8))) short short8v;
typedef __attribute__((ext_vector_type(4))) float float4v;

__device__ inline short f2bf(float f) {
  __hip_bfloat16 h = __float2bfloat16(f);
  return *reinterpret_cast<short*>(&h);
}
__device__ inline float fast_tanh(float x) {
  float e = __expf(2.0f * x);
  return 1.0f - 2.0f * __builtin_amdgcn_rcpf(e + 1.0f);
}

// ---------------- mask dtype detection ----------------
__global__ void k_detect(const unsigned char* m, int* flag) {
  __shared__ int c0, c3;
  if (threadIdx.x == 0) { c0 = 0; c3 = 0; }
  __syncthreads();
  int f0 = 0, f3 = 0;
  for (int i = threadIdx.x; i < 4096; i += 256) {
    unsigned char v = m[i];
    if (v != 0) {
      if ((i & 3) == 0) f0 = 1;
      if ((i & 3) == 3) f3 = 1;
    }
  }
  if (f0) atomicOr(&c0, 1);
  if (f3) atomicOr(&c3, 1);
  __syncthreads();
  if (threadIdx.x == 0) {
    int f;
    if (c3 == 0) f = 0;
    else if (c0 != 0) f = 1;
    else f = 2;
    *flag = f;
  }
}

// proj_head (D x P) -> chunked transposed bf16: out[kc*(P*32) + n*32 + kr]
__global__ void k_trans_head(const float* __restrict__ w, short* __restrict__ out) {
  int idx = blockIdx.x * 256 + threadIdx.x;   // 262144 threads
  int kc  = idx >> 13;
  int j   = idx & 8191;
  int krp = j >> 9;
  int n   = j & 511;
  int k0  = kc * 32 + krp * 2;
  unsigned lo = (unsigned short)f2bf(w[(size_t)k0 * P_ + n]);
  unsigned hi = (unsigned short)f2bf(w[(size_t)(k0 + 1) * P_ + n]);
  ((unsigned*)out)[kc * 8192 + n * 16 + krp] = lo | (hi << 16);
}

// hidden (2 x P x P) -> two chunked transposed bf16 arrays
__global__ void k_trans_hidden(const float* __restrict__ h,
                               short* __restrict__ o0, short* __restrict__ o1) {
  int idx = blockIdx.x * 256 + threadIdx.x;   // 262144 threads
  int which = idx >> 17;
  int j = idx & 131071;
  int kc  = j >> 13;
  int r   = j & 8191;
  int krp = r >> 9;
  int n   = r & 511;
  const float* hs = h + (size_t)which * (P_*P_);
  int k0 = kc * 32 + krp * 2;
  unsigned lo = (unsigned short)f2bf(hs[(size_t)k0 * P_ + n]);
  unsigned hi = (unsigned short)f2bf(hs[(size_t)(k0 + 1) * P_ + n]);
  unsigned* o = (unsigned*)(which ? o1 : o0);
  o[kc * 8192 + n * 16 + krp] = lo | (hi << 16);
}

// pc[b][p] = x[b,254,:]@proj_prep[:,p] + x[b,255,:]@proj_child[:,p]
__global__ void __launch_bounds__(512) k_pc(const float* __restrict__ x,
                                            const float* __restrict__ wp,
                                            const float* __restrict__ wc,
                                            float* __restrict__ pc) {
  __shared__ float xs[16][256];
  int bg = blockIdx.x >> 4, cs = blockIdx.x & 15;
  int t = threadIdx.x;
  int bloc = t >> 5, c = t & 31;
  int batch = bg * 16 + bloc;
  int col = cs * 32 + c;
  float acc = 0.f;
  #pragma unroll
  for (int half = 0; half < 2; half++) {
    const float* wsrc = half ? wc : wp;
    for (int kc = 0; kc < 4; kc++) {
      const float* xr = x + ((size_t)(batch * S_ + SH + half)) * D_ + kc*256 + c*8;
      float4 v0 = *(const float4*)(xr + 0);
      float4 v1 = *(const float4*)(xr + 4);
      __syncthreads();
      *(float4*)&xs[bloc][c*8 + 0] = v0;
      *(float4*)&xs[bloc][c*8 + 4] = v1;
      __syncthreads();
      const float* wv = wsrc + (size_t)(kc*256) * P_ + col;
      #pragma unroll 8
      for (int d = 0; d < 256; d++) {
        acc += xs[bloc][d] * wv[(size_t)d * P_];
      }
    }
  }
  pc[batch * P_ + col] = acc;
}

// ---------------- fused 3-GEMM main kernel ----------------
// 1024 threads = 16 waves, block tile 64 rows x 512 cols; wave = 64r x 32c
// (4 m-tiles x 2 n-tiles = 32 acc/lane). A direct from global (L1-served),
// B direct from L2-resident chunked weights with 1-kc register dbuf.
// LDS: Cs + small buffers = ~77 KB -> 1 block x 16 waves = 4 waves/SIMD.
__global__ void __launch_bounds__(1024, 4) k_main(
    const float* __restrict__ x, const short* __restrict__ wth,
    const short* __restrict__ h0t, const short* __restrict__ h1t,
    const float* __restrict__ scorer, const float* __restrict__ pc,
    float* __restrict__ scores)
{
  __shared__ __attribute__((aligned(16))) short Cs[64*520];    // 66560 B
  __shared__ float scorer_s[P_];
  __shared__ float pcs[2][P_];
  __shared__ float score_ws[64][16];

  const int tid  = threadIdx.x;
  const int lane = tid & 63;
  const int w    = tid >> 6;            // 0..15, column strip w*32
  const int l15  = lane & 15, quad = lane >> 4;
  const int rowbase = blockIdx.x * 64;

  const int bb0 = rowbase / SH;
  const int bb1 = (rowbase + 63) / SH;
  if (tid < P_) {
    scorer_s[tid] = scorer[tid];
    pcs[0][tid] = pc[bb0 * P_ + tid];
    pcs[1][tid] = pc[bb1 * P_ + tid];
  }
  const int lim1 = (bb0 + 1) * SH;

  // per-lane A row offsets (float index into x), one per m-tile
  int aoff[4];
  #pragma unroll
  for (int mt = 0; mt < 4; mt++) {
    int row = rowbase + mt*16 + l15;
    int b = row / SH;
    int s = row - b * SH;
    aoff[mt] = ((b * S_ + s) << 10) + quad * 8;
  }

  const int bcol = (w*32 + l15)*4 + quad;   // uint4 index, nt=0; nt=1 -> +64
  const uint4* wbv = (const uint4*)wth;
  const uint4* h0v = (const uint4*)h0t;
  const uint4* h1v = (const uint4*)h1t;

  float4v acc[4][2];
  #pragma unroll
  for (int i = 0; i < 4; i++) { acc[i][0] = (float4v){0.f,0.f,0.f,0.f};
                                acc[i][1] = (float4v){0.f,0.f,0.f,0.f}; }

  __syncthreads();   // pcs/scorer ready

  // ---- Stage 1: K=1024, 32 chunks; B dbuf in regs; A direct from global ----
  {
    uint4 bc0 = wbv[bcol], bc1 = wbv[bcol + 64];
    for (int kc = 0; kc < 32; kc++) {
      uint4 bn0, bn1;
      if (kc < 31) {
        bn0 = wbv[(size_t)(kc+1)*2048 + bcol];
        bn1 = wbv[(size_t)(kc+1)*2048 + bcol + 64];
      }
      #pragma unroll
      for (int mt = 0; mt < 4; mt++) {
        const float* ap = x + aoff[mt] + kc*32;
        float4 t0 = *(const float4*)ap;
        float4 t1 = *(const float4*)(ap + 4);
        short8v a = { f2bf(t0.x),f2bf(t0.y),f2bf(t0.z),f2bf(t0.w),
                      f2bf(t1.x),f2bf(t1.y),f2bf(t1.z),f2bf(t1.w) };
        acc[mt][0] = __builtin_amdgcn_mfma_f32_16x16x32_bf16(a, *(short8v*)&bc0, acc[mt][0], 0, 0, 0);
        acc[mt][1] = __builtin_amdgcn_mfma_f32_16x16x32_bf16(a, *(short8v*)&bc1, acc[mt][1], 0, 0, 0);
      }
      bc0 = bn0; bc1 = bn1;
    }
  }

  // epilogue 1: + pc bias, tanh -> Cs
  #pragma unroll
  for (int mt = 0; mt < 4; mt++) {
    #pragma unroll
    for (int j = 0; j < 4; j++) {
      int rl = mt*16 + quad*4 + j;
      int rg = rowbase + rl;
      const float* pcb = (rg >= lim1) ? pcs[1] : pcs[0];
      #pragma unroll
      for (int nt = 0; nt < 2; nt++) {
        int col = w*32 + nt*16 + l15;
        float v = fast_tanh(acc[mt][nt][j] + pcb[col]);
        float o = __shfl_xor(v, 1, 64);
        unsigned hs = (unsigned short)f2bf(v);
        unsigned ho = (unsigned short)f2bf(o);
        if ((l15 & 1) == 0)
          *(unsigned*)&Cs[rl*520 + col] = hs | (ho << 16);
      }
    }
  }
  __syncthreads();

  // ---- Stages 2 & 3: K=512, A from Cs (LDS), B direct, reg dbuf ----
  #pragma unroll 1
  for (int stage = 0; stage < 2; stage++) {
    const uint4* hb = stage ? h1v : h0v;
    #pragma unroll
    for (int i = 0; i < 4; i++) { acc[i][0] = (float4v){0.f,0.f,0.f,0.f};
                                  acc[i][1] = (float4v){0.f,0.f,0.f,0.f}; }
    uint4 bc0 = hb[bcol], bc1 = hb[bcol + 64];
    for (int kc = 0; kc < 16; kc++) {
      uint4 bn0, bn1;
      if (kc < 15) {
        bn0 = hb[(size_t)(kc+1)*2048 + bcol];
        bn1 = hb[(size_t)(kc+1)*2048 + bcol + 64];
      }
      #pragma unroll
      for (int mt = 0; mt < 4; mt++) {
        short8v a = *(const short8v*)&Cs[(mt*16 + l15)*520 + kc*32 + quad*8];
        acc[mt][0] = __builtin_amdgcn_mfma_f32_16x16x32_bf16(a, *(short8v*)&bc0, acc[mt][0], 0, 0, 0);
        acc[mt][1] = __builtin_amdgcn_mfma_f32_16x16x32_bf16(a, *(short8v*)&bc1, acc[mt][1], 0, 0, 0);
      }
      bc0 = bn0; bc1 = bn1;
    }

    if (stage == 0) {
      __syncthreads();   // all Cs reads done before overwrite
      #pragma unroll
      for (int mt = 0; mt < 4; mt++) {
        #pragma unroll
        for (int j = 0; j < 4; j++) {
          int rl = mt*16 + quad*4 + j;
          #pragma unroll
          for (int nt = 0; nt < 2; nt++) {
            int col = w*32 + nt*16 + l15;
            float v = fast_tanh(acc[mt][nt][j]);
            float o = __shfl_xor(v, 1, 64);
            unsigned hs = (unsigned short)f2bf(v);
            unsigned ho = (unsigned short)f2bf(o);
            if ((l15 & 1) == 0)
              *(unsigned*)&Cs[rl*520 + col] = hs | (ho << 16);
          }
        }
      }
      __syncthreads();
    }
  }

  // ---- epilogue 3: tanh, scorer dot, reduce ----
  #pragma unroll
  for (int mt = 0; mt < 4; mt++) {
    #pragma unroll
    for (int j = 0; j < 4; j++) {
      int rl = mt*16 + quad*4 + j;
      float part = fast_tanh(acc[mt][0][j]) * scorer_s[w*32 + l15]
                 + fast_tanh(acc[mt][1][j]) * scorer_s[w*32 + 16 + l15];
      #pragma unroll
      for (int o = 1; o < 16; o <<= 1) part += __shfl_xor(part, o, 64);
      if (l15 == 0) score_ws[rl][w] = part;
    }
  }
  __syncthreads();
  if (tid < 64) {
    float s = 0.f;
    #pragma unroll
    for (int k = 0; k < 16; k++) s += score_ws[tid][k];
    scores[rowbase + tid] = __expf(s);
  }
}

// ---------------- masked softmax ----------------
__global__ void __launch_bounds__(256) k_softmax(const float* __restrict__ scores,
                                                 const void* __restrict__ mask,
                                                 const int* __restrict__ flag,
                                                 float* __restrict__ out) {
  int b = blockIdx.x, t = threadIdx.x;
  int lane = t & 63, w = t >> 6;
  __shared__ float ps[4];
  float me = 0.f;
  bool valid = t < SH;
  if (valid) {
    float e = scores[b*SH + t];
    int f = *flag;
    bool mb;
    if (f == 1)      mb = ((const unsigned char*)mask)[b*S_ + t] != 0;
    else if (f == 2) mb = ((const float*)mask)[b*S_ + t] != 0.0f;
    else             mb = ((const int*)mask)[b*S_ + t] != 0;
    me = mb ? e : 0.f;
  }
  float v = me;
  for (int o = 1; o < 64; o <<= 1) v += __shfl_xor(v, o, 64);
  if (lane == 0) ps[w] = v;
  __syncthreads();
  float tot = ps[0] + ps[1] + ps[2] + ps[3] + EPSF;
  if (valid) out[b*SH + t] = me / tot;
}

extern "C" void kernel_launch(void* const* d_in, const int* in_sizes, int n_in,
                              void* d_out, int out_size, void* d_ws, size_t ws_size,
                              hipStream_t stream) {
  const float* x          = (const float*)d_in[0];
  const float* proj_head  = (const float*)d_in[1];
  const float* proj_prep  = (const float*)d_in[2];
  const float* proj_child = (const float*)d_in[3];
  const float* hidden     = (const float*)d_in[4];
  const float* scorer     = (const float*)d_in[5];
  const void*  mask       = d_in[6];
  float* out = (float*)d_out;
  char* ws = (char*)d_ws;

  int*   flag   = (int*)  (ws + 0);
  float* pc     = (float*)(ws + 256);
  short* wth    = (short*)(ws + 524544);
  short* h0t    = (short*)(ws + 1573120);
  short* h1t    = (short*)(ws + 2097408);
  float* scores = (float*)(ws + 2621696);

  k_detect<<<1, 256, 0, stream>>>((const unsigned char*)mask, flag);
  k_trans_head<<<1024, 256, 0, stream>>>(proj_head, wth);
  k_trans_hidden<<<1024, 256, 0, stream>>>(hidden, h0t, h1t);
  k_pc<<<256, 512, 0, stream>>>(x, proj_prep, proj_child, pc);
  k_main<<<1016, 1024, 0, stream>>>(x, wth, h0t, h1t, scorer, pc, scores);
  k_softmax<<<256, 256, 0, stream>>>(scores, mask, flag, out);
}

// Round 6
// 665.368 us; speedup vs baseline: 1.5698x; 1.5698x over previous
//
#include <hip/hip_runtime.h>
#include <hip/hip_bf16.h>
#include <stdint.h>

#define B_ 256
#define S_ 256
#define D_ 1024
#define P_ 512
#define SH 254            /* S-2 */
#define M_ (B_*SH)        /* 65024 */
#define EPSF 1e-7f

typedef __attribute__((ext_vector_type(8))) short short8v;
typedef __attribute__((ext_vector_type(4))) float float4v;

__device__ inline short f2bf(float f) {
  __hip_bfloat16 h = __float2bfloat16(f);
  return *reinterpret_cast<short*>(&h);
}
__device__ inline float fast_tanh(float x) {
  float e = __expf(2.0f * x);
  return 1.0f - 2.0f * __builtin_amdgcn_rcpf(e + 1.0f);
}

// ---------------- mask dtype detection ----------------
__global__ void k_detect(const unsigned char* m, int* flag) {
  __shared__ int c0, c3;
  if (threadIdx.x == 0) { c0 = 0; c3 = 0; }
  __syncthreads();
  int f0 = 0, f3 = 0;
  for (int i = threadIdx.x; i < 4096; i += 256) {
    unsigned char v = m[i];
    if (v != 0) {
      if ((i & 3) == 0) f0 = 1;
      if ((i & 3) == 3) f3 = 1;
    }
  }
  if (f0) atomicOr(&c0, 1);
  if (f3) atomicOr(&c3, 1);
  __syncthreads();
  if (threadIdx.x == 0) {
    int f;
    if (c3 == 0) f = 0;
    else if (c0 != 0) f = 1;
    else f = 2;
    *flag = f;
  }
}

// proj_head (D x P) -> chunked transposed bf16: out[kc*(P*32) + n*32 + kr]
__global__ void k_trans_head(const float* __restrict__ w, short* __restrict__ out) {
  int idx = blockIdx.x * 256 + threadIdx.x;   // 262144 threads
  int kc  = idx >> 13;
  int j   = idx & 8191;
  int krp = j >> 9;
  int n   = j & 511;
  int k0  = kc * 32 + krp * 2;
  unsigned lo = (unsigned short)f2bf(w[(size_t)k0 * P_ + n]);
  unsigned hi = (unsigned short)f2bf(w[(size_t)(k0 + 1) * P_ + n]);
  ((unsigned*)out)[kc * 8192 + n * 16 + krp] = lo | (hi << 16);
}

// hidden (2 x P x P) -> two chunked transposed bf16 arrays
__global__ void k_trans_hidden(const float* __restrict__ h,
                               short* __restrict__ o0, short* __restrict__ o1) {
  int idx = blockIdx.x * 256 + threadIdx.x;   // 262144 threads
  int which = idx >> 17;
  int j = idx & 131071;
  int kc  = j >> 13;
  int r   = j & 8191;
  int krp = r >> 9;
  int n   = r & 511;
  const float* hs = h + (size_t)which * (P_*P_);
  int k0 = kc * 32 + krp * 2;
  unsigned lo = (unsigned short)f2bf(hs[(size_t)k0 * P_ + n]);
  unsigned hi = (unsigned short)f2bf(hs[(size_t)(k0 + 1) * P_ + n]);
  unsigned* o = (unsigned*)(which ? o1 : o0);
  o[kc * 8192 + n * 16 + krp] = lo | (hi << 16);
}

// pc[b][p] = x[b,254,:]@proj_prep[:,p] + x[b,255,:]@proj_child[:,p]
__global__ void __launch_bounds__(512) k_pc(const float* __restrict__ x,
                                            const float* __restrict__ wp,
                                            const float* __restrict__ wc,
                                            float* __restrict__ pc) {
  __shared__ float xs[16][256];
  int bg = blockIdx.x >> 4, cs = blockIdx.x & 15;
  int t = threadIdx.x;
  int bloc = t >> 5, c = t & 31;
  int batch = bg * 16 + bloc;
  int col = cs * 32 + c;
  float acc = 0.f;
  #pragma unroll
  for (int half = 0; half < 2; half++) {
    const float* wsrc = half ? wc : wp;
    for (int kc = 0; kc < 4; kc++) {
      const float* xr = x + ((size_t)(batch * S_ + SH + half)) * D_ + kc*256 + c*8;
      float4 v0 = *(const float4*)(xr + 0);
      float4 v1 = *(const float4*)(xr + 4);
      __syncthreads();
      *(float4*)&xs[bloc][c*8 + 0] = v0;
      *(float4*)&xs[bloc][c*8 + 4] = v1;
      __syncthreads();
      const float* wv = wsrc + (size_t)(kc*256) * P_ + col;
      #pragma unroll 8
      for (int d = 0; d < 256; d++) {
        acc += xs[bloc][d] * wv[(size_t)d * P_];
      }
    }
  }
  pc[batch * P_ + col] = acc;
}

// ---------------- fused 3-GEMM main kernel ----------------
// 1024 threads = 16 waves (4/SIMD), tile 64 rows x 512 cols; wave = 64r x 32c
// (acc[4][2] = 32 AGPR). A staged COALESCED into dbuf LDS (BK=128, loads a
// full super-chunk ahead); B direct from L2-resident chunked weights with
// per-kc register dbuf (each wave owns a distinct 32-col strip).
__global__ void __launch_bounds__(1024, 4) k_main(
    const float* __restrict__ x, const short* __restrict__ wth,
    const short* __restrict__ h0t, const short* __restrict__ h1t,
    const float* __restrict__ scorer, const float* __restrict__ pc,
    float* __restrict__ scores)
{
  __shared__ __attribute__((aligned(16))) short As[2][64*136];  // 34816 B
  __shared__ __attribute__((aligned(16))) short Cs[64*520];     // 66560 B
  __shared__ float scorer_s[P_];
  __shared__ float pcs[2][P_];
  __shared__ float score_ws[64][16];

  const int tid  = threadIdx.x;
  const int lane = tid & 63;
  const int w    = tid >> 6;            // 0..15, column strip w*32
  const int l15  = lane & 15, quad = lane >> 4;
  const int rowbase = blockIdx.x * 64;

  const int bb0 = rowbase / SH;
  const int bb1 = (rowbase + 63) / SH;
  if (tid < P_) {
    scorer_s[tid] = scorer[tid];
    pcs[0][tid] = pc[bb0 * P_ + tid];
    pcs[1][tid] = pc[bb1 * P_ + tid];
  }
  const int lim1 = (bb0 + 1) * SH;

  // A staging map: thread -> (row = tid>>4, 8 floats at k = (tid&15)*8)
  const int srow = tid >> 4;
  const int skg  = (tid & 15) * 8;
  const float* sptr;
  {
    int r0 = rowbase + srow;
    int ab = r0 / SH;
    int as_ = r0 - ab * SH;
    sptr = x + ((size_t)(ab * S_ + as_)) * D_ + skg;
  }

  const int bcol = (w*32 + l15)*4 + quad;   // uint4 index; nt=1 -> +64
  const uint4* wbv = (const uint4*)wth;
  const uint4* h0v = (const uint4*)h0t;
  const uint4* h1v = (const uint4*)h1t;

  float4v acc[4][2];
  #pragma unroll
  for (int i = 0; i < 4; i++) { acc[i][0] = (float4v){0.f,0.f,0.f,0.f};
                                acc[i][1] = (float4v){0.f,0.f,0.f,0.f}; }

  // preload A super-chunk 0 (coalesced: 16 threads cover one row's 512 B)
  {
    float4 t0 = *(const float4*)(sptr + 0);
    float4 t1 = *(const float4*)(sptr + 4);
    short8v s = { f2bf(t0.x),f2bf(t0.y),f2bf(t0.z),f2bf(t0.w),
                  f2bf(t1.x),f2bf(t1.y),f2bf(t1.z),f2bf(t1.w) };
    *(short8v*)&As[0][srow*136 + skg] = s;
  }
  __syncthreads();

  // ---- Stage 1: K=1024, 8 super-chunks of 128; A LDS dbuf; B reg dbuf ----
  {
    uint4 bc0 = wbv[bcol], bc1 = wbv[bcol + 64];
    for (int sc = 0; sc < 8; sc++) {
      const int cur = sc & 1;
      float4 n0, n1;
      if (sc < 7) {
        const float* p = sptr + (sc + 1) * 128;
        n0 = *(const float4*)(p + 0);
        n1 = *(const float4*)(p + 4);
      }
      #pragma unroll
      for (int c = 0; c < 4; c++) {
        const int kc = sc * 4 + c;
        uint4 bn0, bn1;
        if (kc < 31) {
          bn0 = wbv[(size_t)(kc+1)*2048 + bcol];
          bn1 = wbv[(size_t)(kc+1)*2048 + bcol + 64];
        }
        #pragma unroll
        for (int mt = 0; mt < 4; mt++) {
          short8v a = *(const short8v*)&As[cur][(mt*16 + l15)*136 + c*32 + quad*8];
          acc[mt][0] = __builtin_amdgcn_mfma_f32_16x16x32_bf16(a, *(short8v*)&bc0, acc[mt][0], 0, 0, 0);
          acc[mt][1] = __builtin_amdgcn_mfma_f32_16x16x32_bf16(a, *(short8v*)&bc1, acc[mt][1], 0, 0, 0);
        }
        bc0 = bn0; bc1 = bn1;
      }
      if (sc < 7) {
        short8v s = { f2bf(n0.x),f2bf(n0.y),f2bf(n0.z),f2bf(n0.w),
                      f2bf(n1.x),f2bf(n1.y),f2bf(n1.z),f2bf(n1.w) };
        *(short8v*)&As[cur ^ 1][srow*136 + skg] = s;
      }
      __syncthreads();
    }
  }

  // epilogue 1: + pc bias, tanh -> Cs
  #pragma unroll
  for (int mt = 0; mt < 4; mt++) {
    #pragma unroll
    for (int j = 0; j < 4; j++) {
      int rl = mt*16 + quad*4 + j;
      int rg = rowbase + rl;
      const float* pcb = (rg >= lim1) ? pcs[1] : pcs[0];
      #pragma unroll
      for (int nt = 0; nt < 2; nt++) {
        int col = w*32 + nt*16 + l15;
        float v = fast_tanh(acc[mt][nt][j] + pcb[col]);
        float o = __shfl_xor(v, 1, 64);
        unsigned hs = (unsigned short)f2bf(v);
        unsigned ho = (unsigned short)f2bf(o);
        if ((l15 & 1) == 0)
          *(unsigned*)&Cs[rl*520 + col] = hs | (ho << 16);
      }
    }
  }
  __syncthreads();

  // ---- Stages 2 & 3: K=512, A from Cs (LDS), B direct, reg dbuf ----
  #pragma unroll 1
  for (int stage = 0; stage < 2; stage++) {
    const uint4* hb = stage ? h1v : h0v;
    #pragma unroll
    for (int i = 0; i < 4; i++) { acc[i][0] = (float4v){0.f,0.f,0.f,0.f};
                                  acc[i][1] = (float4v){0.f,0.f,0.f,0.f}; }
    uint4 bc0 = hb[bcol], bc1 = hb[bcol + 64];
    for (int kc = 0; kc < 16; kc++) {
      uint4 bn0, bn1;
      if (kc < 15) {
        bn0 = hb[(size_t)(kc+1)*2048 + bcol];
        bn1 = hb[(size_t)(kc+1)*2048 + bcol + 64];
      }
      #pragma unroll
      for (int mt = 0; mt < 4; mt++) {
        short8v a = *(const short8v*)&Cs[(mt*16 + l15)*520 + kc*32 + quad*8];
        acc[mt][0] = __builtin_amdgcn_mfma_f32_16x16x32_bf16(a, *(short8v*)&bc0, acc[mt][0], 0, 0, 0);
        acc[mt][1] = __builtin_amdgcn_mfma_f32_16x16x32_bf16(a, *(short8v*)&bc1, acc[mt][1], 0, 0, 0);
      }
      bc0 = bn0; bc1 = bn1;
    }

    if (stage == 0) {
      __syncthreads();   // all Cs reads done before overwrite
      #pragma unroll
      for (int mt = 0; mt < 4; mt++) {
        #pragma unroll
        for (int j = 0; j < 4; j++) {
          int rl = mt*16 + quad*4 + j;
          #pragma unroll
          for (int nt = 0; nt < 2; nt++) {
            int col = w*32 + nt*16 + l15;
            float v = fast_tanh(acc[mt][nt][j]);
            float o = __shfl_xor(v, 1, 64);
            unsigned hs = (unsigned short)f2bf(v);
            unsigned ho = (unsigned short)f2bf(o);
            if ((l15 & 1) == 0)
              *(unsigned*)&Cs[rl*520 + col] = hs | (ho << 16);
          }
        }
      }
      __syncthreads();
    }
  }

  // ---- epilogue 3: tanh, scorer dot, reduce ----
  #pragma unroll
  for (int mt = 0; mt < 4; mt++) {
    #pragma unroll
    for (int j = 0; j < 4; j++) {
      int rl = mt*16 + quad*4 + j;
      float part = fast_tanh(acc[mt][0][j]) * scorer_s[w*32 + l15]
                 + fast_tanh(acc[mt][1][j]) * scorer_s[w*32 + 16 + l15];
      #pragma unroll
      for (int o = 1; o < 16; o <<= 1) part += __shfl_xor(part, o, 64);
      if (l15 == 0) score_ws[rl][w] = part;
    }
  }
  __syncthreads();
  if (tid < 64) {
    float s = 0.f;
    #pragma unroll
    for (int k = 0; k < 16; k++) s += score_ws[tid][k];
    scores[rowbase + tid] = __expf(s);
  }
}

// ---------------- masked softmax ----------------
__global__ void __launch_bounds__(256) k_softmax(const float* __restrict__ scores,
                                                 const void* __restrict__ mask,
                                                 const int* __restrict__ flag,
                                                 float* __restrict__ out) {
  int b = blockIdx.x, t = threadIdx.x;
  int lane = t & 63, w = t >> 6;
  __shared__ float ps[4];
  float me = 0.f;
  bool valid = t < SH;
  if (valid) {
    float e = scores[b*SH + t];
    int f = *flag;
    bool mb;
    if (f == 1)      mb = ((const unsigned char*)mask)[b*S_ + t] != 0;
    else if (f == 2) mb = ((const float*)mask)[b*S_ + t] != 0.0f;
    else             mb = ((const int*)mask)[b*S_ + t] != 0;
    me = mb ? e : 0.f;
  }
  float v = me;
  for (int o = 1; o < 64; o <<= 1) v += __shfl_xor(v, o, 64);
  if (lane == 0) ps[w] = v;
  __syncthreads();
  float tot = ps[0] + ps[1] + ps[2] + ps[3] + EPSF;
  if (valid) out[b*SH + t] = me / tot;
}

extern "C" void kernel_launch(void* const* d_in, const int* in_sizes, int n_in,
                              void* d_out, int out_size, void* d_ws, size_t ws_size,
                              hipStream_t stream) {
  const float* x          = (const float*)d_in[0];
  const float* proj_head  = (const float*)d_in[1];
  const float* proj_prep  = (const float*)d_in[2];
  const float* proj_child = (const float*)d_in[3];
  const float* hidden     = (const float*)d_in[4];
  const float* scorer     = (const float*)d_in[5];
  const void*  mask       = d_in[6];
  float* out = (float*)d_out;
  char* ws = (char*)d_ws;

  int*   flag   = (int*)  (ws + 0);
  float* pc     = (float*)(ws + 256);
  short* wth    = (short*)(ws + 524544);
  short* h0t    = (short*)(ws + 1573120);
  short* h1t    = (short*)(ws + 2097408);
  float* scores = (float*)(ws + 2621696);

  k_detect<<<1, 256, 0, stream>>>((const unsigned char*)mask, flag);
  k_trans_head<<<1024, 256, 0, stream>>>(proj_head, wth);
  k_trans_hidden<<<1024, 256, 0, stream>>>(hidden, h0t, h1t);
  k_pc<<<256, 512, 0, stream>>>(x, proj_prep, proj_child, pc);
  k_main<<<1016, 1024, 0, stream>>>(x, wth, h0t, h1t, scorer, pc, scores);
  k_softmax<<<256, 256, 0, stream>>>(scores, mask, flag, out);
}